// Round 1
// baseline (1606.014 us; speedup 1.0000x reference)
//
#include <hip/hip_runtime.h>
#include <hip/hip_bf16.h>

typedef short bf16x8 __attribute__((ext_vector_type(8)));
typedef float f32x4  __attribute__((ext_vector_type(4)));

#define B_ 4
#define H_ 16
#define S_ 2048
#define D_ 64
#define QT 64
#define KT 64
#define NT (S_ / KT)
#define LDE 72   // LDS row stride in bf16 elements (= 36 dwords)

__device__ __forceinline__ unsigned short f2bf(float x) {
  union { float f; unsigned int u; } v; v.f = x;
  unsigned int r = v.u + 0x7fffu + ((v.u >> 16) & 1u);  // RNE
  return (unsigned short)(r >> 16);
}
__device__ __forceinline__ float bf2f(unsigned int u) {
  union { unsigned int u; float f; } v; v.u = u << 16;
  return v.f;
}

__global__ __launch_bounds__(256, 4)
void attn_fused(const float* __restrict__ Qg, const float* __restrict__ Kg,
                const float* __restrict__ Vg, const int* __restrict__ Mg,
                float* __restrict__ Og, float* __restrict__ Ag)
{
  __shared__ __align__(16) unsigned short Ksh[KT * LDE];
  __shared__ __align__(16) unsigned short Vsh[D_ * LDE];
  __shared__ __align__(16) unsigned short Psh[QT * LDE];

  const int tid  = threadIdx.x;
  const int lane = tid & 63;
  const int wv   = tid >> 6;
  const int lg   = lane >> 4;
  const int ln   = lane & 15;

  const int b  = blockIdx.z;
  const int h  = blockIdx.y;
  const int q0 = blockIdx.x * QT;

  const float* Qp = Qg + (((long)(b * H_ + h)) * S_ + q0) * D_;
  const float* Kp = Kg + ((long)(b * H_ + h)) * S_ * D_;
  const float* Vp = Vg + ((long)(b * H_ + h)) * S_ * D_;
  const int*   Mp = Mg + (long)b * S_ * S_ + (long)q0 * S_;
  float* Op = Og + (((long)(b * H_ + h)) * S_ + q0) * D_;
  float* Ap = Ag + (((long)(b * H_ + h)) * S_ + q0) * S_;

  const int srow = tid >> 2;   // 0..63 staging row
  const int scol = tid & 3;    // 0..3 chunk-of-16
  const int c8   = tid & 7;    // V staging: d-chunk of 8
  const int kp   = tid >> 3;   // V staging: k-pair 0..31

  // ---- stage Q (pre-scaled by 1/sqrt(D)=0.125, exact) into Ksh, pull A-frags ----
  {
    const float4* src = reinterpret_cast<const float4*>(Qp + srow * D_ + scol * 16);
    unsigned int pk[8];
#pragma unroll
    for (int i = 0; i < 4; ++i) {
      float4 x = src[i];
      pk[2*i]   = (unsigned)f2bf(x.x * 0.125f) | ((unsigned)f2bf(x.y * 0.125f) << 16);
      pk[2*i+1] = (unsigned)f2bf(x.z * 0.125f) | ((unsigned)f2bf(x.w * 0.125f) << 16);
    }
    uint4* dst = reinterpret_cast<uint4*>(&Ksh[srow * LDE + scol * 16]);
    dst[0] = make_uint4(pk[0], pk[1], pk[2], pk[3]);
    dst[1] = make_uint4(pk[4], pk[5], pk[6], pk[7]);
  }
  __syncthreads();

  bf16x8 aq[2];   // Q A-frags: A[m=ln][k], rows 16*wv..+15, held all kernel
#pragma unroll
  for (int ks = 0; ks < 2; ++ks)
    aq[ks] = *reinterpret_cast<const bf16x8*>(&Ksh[(wv * 16 + ln) * LDE + ks * 32 + lg * 8]);

  const int qrow = wv * 16 + lg * 4;   // base row of this lane's 4 C/D rows

  float m[4], l[4];
#pragma unroll
  for (int r = 0; r < 4; ++r) { m[r] = -1e30f; l[r] = 0.0f; }

  // =============== phase 1: running row max + denom ===============
#pragma unroll 1
  for (int kt = 0; kt < NT; ++kt) {
    __syncthreads();
    {
      const float4* src = reinterpret_cast<const float4*>(Kp + ((long)kt * KT + srow) * D_ + scol * 16);
      unsigned int pk[8];
#pragma unroll
      for (int i = 0; i < 4; ++i) {
        float4 x = src[i];
        pk[2*i]   = (unsigned)f2bf(x.x) | ((unsigned)f2bf(x.y) << 16);
        pk[2*i+1] = (unsigned)f2bf(x.z) | ((unsigned)f2bf(x.w) << 16);
      }
      uint4* dst = reinterpret_cast<uint4*>(&Ksh[srow * LDE + scol * 16]);
      dst[0] = make_uint4(pk[0], pk[1], pk[2], pk[3]);
      dst[1] = make_uint4(pk[4], pk[5], pk[6], pk[7]);
    }
    __syncthreads();

    f32x4 acc[4];
#pragma unroll
    for (int f = 0; f < 4; ++f) acc[f] = (f32x4){0.f, 0.f, 0.f, 0.f};
#pragma unroll
    for (int ks = 0; ks < 2; ++ks)
#pragma unroll
      for (int f = 0; f < 4; ++f) {
        bf16x8 bk = *reinterpret_cast<const bf16x8*>(&Ksh[(f * 16 + ln) * LDE + ks * 32 + lg * 8]);
        acc[f] = __builtin_amdgcn_mfma_f32_16x16x32_bf16(aq[ks], bk, acc[f], 0, 0, 0);
      }

#pragma unroll
    for (int f = 0; f < 4; ++f)
#pragma unroll
      for (int r = 0; r < 4; ++r) {
        int mv = Mp[(qrow + r) * S_ + kt * KT + f * 16 + ln];
        acc[f][r] = mv ? acc[f][r] : -1e14f;
      }

#pragma unroll
    for (int r = 0; r < 4; ++r) {
      float tm = fmaxf(fmaxf(acc[0][r], acc[1][r]), fmaxf(acc[2][r], acc[3][r]));
      tm = fmaxf(tm, __shfl_xor(tm, 1));
      tm = fmaxf(tm, __shfl_xor(tm, 2));
      tm = fmaxf(tm, __shfl_xor(tm, 4));
      tm = fmaxf(tm, __shfl_xor(tm, 8));
      float mn = fmaxf(m[r], tm);
      float alpha = __expf(m[r] - mn);
      float ps = __expf(acc[0][r] - mn) + __expf(acc[1][r] - mn)
               + __expf(acc[2][r] - mn) + __expf(acc[3][r] - mn);
      ps += __shfl_xor(ps, 1);
      ps += __shfl_xor(ps, 2);
      ps += __shfl_xor(ps, 4);
      ps += __shfl_xor(ps, 8);
      l[r] = l[r] * alpha + ps;
      m[r] = mn;
    }
  }

  float rl[4];
#pragma unroll
  for (int r = 0; r < 4; ++r) rl[r] = 1.0f / l[r];

  f32x4 oacc[4];
#pragma unroll
  for (int f = 0; f < 4; ++f) oacc[f] = (f32x4){0.f, 0.f, 0.f, 0.f};

  // =============== phase 2: recompute scores, write attn, PV ===============
#pragma unroll 1
  for (int kt = 0; kt < NT; ++kt) {
    __syncthreads();
    {
      const float4* src = reinterpret_cast<const float4*>(Kp + ((long)kt * KT + srow) * D_ + scol * 16);
      unsigned int pk[8];
#pragma unroll
      for (int i = 0; i < 4; ++i) {
        float4 x = src[i];
        pk[2*i]   = (unsigned)f2bf(x.x) | ((unsigned)f2bf(x.y) << 16);
        pk[2*i+1] = (unsigned)f2bf(x.z) | ((unsigned)f2bf(x.w) << 16);
      }
      uint4* dst = reinterpret_cast<uint4*>(&Ksh[srow * LDE + scol * 16]);
      dst[0] = make_uint4(pk[0], pk[1], pk[2], pk[3]);
      dst[1] = make_uint4(pk[4], pk[5], pk[6], pk[7]);
    }
    {
      // V staged transposed Vsh[d][k], dword = 2 adjacent k, XOR-swizzled dword
      // groups so transpose-writes are <=2-way and frag reads stay one aligned b128.
      const float* v0 = Vp + ((long)kt * KT + 2 * kp) * D_ + c8 * 8;
      float4 a0 = *reinterpret_cast<const float4*>(v0);
      float4 a1 = *reinterpret_cast<const float4*>(v0 + 4);
      float4 b0 = *reinterpret_cast<const float4*>(v0 + D_);
      float4 b1 = *reinterpret_cast<const float4*>(v0 + D_ + 4);
      float lo[8] = {a0.x, a0.y, a0.z, a0.w, a1.x, a1.y, a1.z, a1.w};
      float hi[8] = {b0.x, b0.y, b0.z, b0.w, b1.x, b1.y, b1.z, b1.w};
      unsigned int* V32 = reinterpret_cast<unsigned int*>(Vsh);
#pragma unroll
      for (int j = 0; j < 8; ++j) {
        unsigned int pk2 = (unsigned)f2bf(lo[j]) | ((unsigned)f2bf(hi[j]) << 16);
        V32[(c8 * 8 + j) * 36 + ((kp + 4 * c8) & 31)] = pk2;
      }
    }
    __syncthreads();

    f32x4 acc[4];
#pragma unroll
    for (int f = 0; f < 4; ++f) acc[f] = (f32x4){0.f, 0.f, 0.f, 0.f};
#pragma unroll
    for (int ks = 0; ks < 2; ++ks)
#pragma unroll
      for (int f = 0; f < 4; ++f) {
        bf16x8 bk = *reinterpret_cast<const bf16x8*>(&Ksh[(f * 16 + ln) * LDE + ks * 32 + lg * 8]);
        acc[f] = __builtin_amdgcn_mfma_f32_16x16x32_bf16(aq[ks], bk, acc[f], 0, 0, 0);
      }

#pragma unroll
    for (int f = 0; f < 4; ++f)
#pragma unroll
      for (int r = 0; r < 4; ++r) {
        int mv = Mp[(qrow + r) * S_ + kt * KT + f * 16 + ln];
        float s = mv ? acc[f][r] : -1e14f;           // masked: expf underflows to exact 0
        float p = __expf(s - m[r]) * rl[r];
        Psh[(qrow + r) * LDE + f * 16 + ln] = f2bf(p);
      }
    __syncthreads();

    // attn global write: coalesced float4, values == bf16-rounded p (consistent with PV)
    {
      const int prow = wv * 16 + (srow & 15);
      const uint4* psrc = reinterpret_cast<const uint4*>(&Psh[prow * LDE + scol * 16]);
      uint4 u0 = psrc[0], u1 = psrc[1];
      unsigned int uu[8] = {u0.x, u0.y, u0.z, u0.w, u1.x, u1.y, u1.z, u1.w};
      float4* dst = reinterpret_cast<float4*>(Ap + (long)prow * S_ + kt * KT + scol * 16);
#pragma unroll
      for (int i = 0; i < 4; ++i) {
        float4 o;
        o.x = bf2f(uu[2*i] & 0xffffu);
        o.y = bf2f(uu[2*i] >> 16);
        o.z = bf2f(uu[2*i+1] & 0xffffu);
        o.w = bf2f(uu[2*i+1] >> 16);
        dst[i] = o;
      }
    }

    // PV accumulate: A = P (own wave's rows), B = swizzled V^T
    bf16x8 pa[2];
#pragma unroll
    for (int ks = 0; ks < 2; ++ks)
      pa[ks] = *reinterpret_cast<const bf16x8*>(&Psh[(wv * 16 + ln) * LDE + ks * 32 + lg * 8]);
#pragma unroll
    for (int ks = 0; ks < 2; ++ks)
#pragma unroll
      for (int f2 = 0; f2 < 4; ++f2) {
        int drow = f2 * 16 + ln;
        int gsw = (4 * ks + lg + ((drow >> 3) & 7)) & 7;
        bf16x8 bv = *reinterpret_cast<const bf16x8*>(&Vsh[drow * LDE + gsw * 8]);
        oacc[f2] = __builtin_amdgcn_mfma_f32_16x16x32_bf16(pa[ks], bv, oacc[f2], 0, 0, 0);
      }
  }

  // epilogue: out (fp32 accumulators, already normalized since P was normalized)
#pragma unroll
  for (int f2 = 0; f2 < 4; ++f2)
#pragma unroll
    for (int r = 0; r < 4; ++r)
      Op[(qrow + r) * D_ + f2 * 16 + ln] = oacc[f2][r];
}

extern "C" void kernel_launch(void* const* d_in, const int* in_sizes, int n_in,
                              void* d_out, int out_size, void* d_ws, size_t ws_size,
                              hipStream_t stream) {
  const float* Q = (const float*)d_in[0];
  const float* K = (const float*)d_in[1];
  const float* V = (const float*)d_in[2];
  const int*   M = (const int*)d_in[3];
  float* out  = (float*)d_out;
  float* attn = out + (long)B_ * H_ * S_ * D_;   // tuple: [out | attn]
  dim3 grid(S_ / QT, H_, B_);
  attn_fused<<<grid, 256, 0, stream>>>(Q, K, V, M, out, attn);
}